// Round 9
// baseline (212.735 us; speedup 1.0000x reference)
//
#include <hip/hip_runtime.h>
#include <hip/hip_bf16.h>
#include <math.h>

#define OUT0   2097152      // 4*1024*512 (output 0 size)
#define SP_EPS 1e-7f
#define CEXP   0.18033688011112042f   // 0.125 * log2(e): exp(s/8) == exp2(s*CEXP)

typedef __attribute__((ext_vector_type(8))) short bf16x8;
typedef __attribute__((ext_vector_type(4))) float f32x4;

// ---------------- bf16 split helpers (RN-to-nearest-even) ------------------
__device__ __forceinline__ unsigned short f2bf(float f) {
  unsigned int b = __float_as_uint(f);
  return (unsigned short)((b + 0x7fffu + ((b >> 16) & 1u)) >> 16);
}
__device__ __forceinline__ float bf2f(unsigned short u) {
  return __uint_as_float(((unsigned int)u) << 16);
}

// merge two sorted-desc 6-lists (in a[], b[]) -> top-6 of union, sorted desc, into a[]
__device__ __forceinline__ void merge6(float a[6], const float b[6]) {
  float m0 = fmaxf(a[0], b[5]), m1 = fmaxf(a[1], b[4]), m2 = fmaxf(a[2], b[3]),
        m3 = fmaxf(a[3], b[2]), m4 = fmaxf(a[4], b[1]), m5 = fmaxf(a[5], b[0]);
  float x;
  x = fmaxf(m0, m3); m3 = fminf(m0, m3); m0 = x;
  x = fmaxf(m1, m4); m4 = fminf(m1, m4); m1 = x;
  x = fmaxf(m2, m5); m5 = fminf(m2, m5); m2 = x;
  x = fmaxf(m0, m1); m1 = fminf(m0, m1); m0 = x;
  x = fmaxf(m0, m2); m2 = fminf(m0, m2); m0 = x;
  x = fmaxf(m1, m2); m2 = fminf(m1, m2); m1 = x;
  x = fmaxf(m3, m4); m4 = fminf(m3, m4); m3 = x;
  x = fmaxf(m3, m5); m5 = fminf(m3, m5); m3 = x;
  x = fmaxf(m4, m5); m5 = fminf(m4, m5); m4 = x;
  a[0] = m0; a[1] = m1; a[2] = m2; a[3] = m3; a[4] = m4; a[5] = m5;
}

// ---------------- kernel Z: zero-fill the attn region (128 MB) -------------
__global__ __launch_bounds__(256) void zerofill_kernel(float4* __restrict__ p, int n4) {
  const int stride = gridDim.x * 256;
  for (int i = blockIdx.x * 256 + threadIdx.x; i < n4; i += stride)
    p[i] = make_float4(0.f, 0.f, 0.f, 0.f);
}

// ---------------- kernel 0: split-convert up to 3 weight matrices ----------
__global__ __launch_bounds__(256) void convW_kernel(
    const float* __restrict__ w0, const float* __restrict__ w1,
    const float* __restrict__ w2, unsigned short* __restrict__ dst)
{
  const int z = blockIdx.z;
  const float* src = (z == 0) ? w0 : (z == 1) ? w1 : w2;
  unsigned short* hi = dst + (size_t)z * (1u << 19);
  unsigned short* lo = hi + (1u << 18);
  const int i = (blockIdx.x * 256 + threadIdx.x) * 4;
  const float4 x = *(const float4*)(src + i);
  ushort4 h, l;
  h.x = f2bf(x.x); l.x = f2bf(x.x - bf2f(h.x));
  h.y = f2bf(x.y); l.y = f2bf(x.y - bf2f(h.y));
  h.z = f2bf(x.z); l.z = f2bf(x.z - bf2f(h.z));
  h.w = f2bf(x.w); l.w = f2bf(x.w - bf2f(h.w));
  *(ushort4*)(hi + i) = h;
  *(ushort4*)(lo + i) = l;
}

// ---------------- kernel 1: QKV projection via split-bf16 MFMA -------------
__global__ __launch_bounds__(256) void qkv_mfma_kernel(
    const float* __restrict__ q, const float* __restrict__ k, const float* __restrict__ v,
    const unsigned short* __restrict__ Wsplit,
    const float* __restrict__ bq, const float* __restrict__ bk, const float* __restrict__ bv,
    unsigned short* __restrict__ qhh, unsigned short* __restrict__ qhl,
    unsigned short* __restrict__ khh, unsigned short* __restrict__ khl,
    float* __restrict__ vh)
{
  __shared__ short Ash[64 * 64], Asl[64 * 64];
  __shared__ short Bsh[128 * 64], Bsl[128 * 64];
  const int z = blockIdx.z;
  const float* A = (z == 0) ? q : (z == 1) ? k : v;
  const unsigned short* Wh = Wsplit + (size_t)z * (1u << 19);
  const unsigned short* Wl = Wh + (1u << 18);
  const float* bias = (z == 0) ? bq : (z == 1) ? bk : bv;
  const int r0 = blockIdx.x * 64, n0 = blockIdx.y * 128;
  const int tid = threadIdx.x, lane = tid & 63, w = tid >> 6;
  const int wr = w >> 1, wc = w & 1;
  const int l15 = lane & 15, l4 = lane >> 4;

  f32x4 acc[2][4];
#pragma unroll
  for (int a = 0; a < 2; ++a)
#pragma unroll
    for (int b = 0; b < 4; ++b) acc[a][b] = (f32x4){0.f, 0.f, 0.f, 0.f};

  for (int kt = 0; kt < 8; ++kt) {
    __syncthreads();
#pragma unroll
    for (int p = 0; p < 2; ++p) {
      const int c = tid + p * 256, row = c >> 3, k8 = (c & 7) * 8;
      const float4 x0 = *(const float4*)(A + (size_t)(r0 + row) * 512 + kt * 64 + k8);
      const float4 x1 = *(const float4*)(A + (size_t)(r0 + row) * 512 + kt * 64 + k8 + 4);
      bf16x8 hv, lv;
      const float xs[8] = {x0.x, x0.y, x0.z, x0.w, x1.x, x1.y, x1.z, x1.w};
#pragma unroll
      for (int j = 0; j < 8; ++j) {
        const unsigned short h = f2bf(xs[j]);
        hv[j] = (short)h; lv[j] = (short)f2bf(xs[j] - bf2f(h));
      }
      const int si = row * 64 + (k8 ^ ((row & 7) << 3));
      *(bf16x8*)&Ash[si] = hv; *(bf16x8*)&Asl[si] = lv;
    }
#pragma unroll
    for (int p = 0; p < 4; ++p) {
      const int c = tid + p * 256, row = c >> 3, k8 = (c & 7) * 8;
      const size_t go = (size_t)(n0 + row) * 512 + kt * 64 + k8;
      const int si = row * 64 + (k8 ^ ((row & 7) << 3));
      *(bf16x8*)&Bsh[si] = *(const bf16x8*)(Wh + go);
      *(bf16x8*)&Bsl[si] = *(const bf16x8*)(Wl + go);
    }
    __syncthreads();
#pragma unroll
    for (int kf = 0; kf < 2; ++kf) {
      const int kb = kf * 32 + l4 * 8;
      bf16x8 ah[2], al2[2];
#pragma unroll
      for (int rb = 0; rb < 2; ++rb) {
        const int ar = wr * 32 + rb * 16 + l15;
        const int si = ar * 64 + (kb ^ ((ar & 7) << 3));
        ah[rb] = *(bf16x8*)&Ash[si]; al2[rb] = *(bf16x8*)&Asl[si];
      }
#pragma unroll
      for (int cb = 0; cb < 4; ++cb) {
        const int br = wc * 64 + cb * 16 + l15;
        const int si = br * 64 + (kb ^ ((br & 7) << 3));
        const bf16x8 bh = *(bf16x8*)&Bsh[si];
        const bf16x8 bl = *(bf16x8*)&Bsl[si];
#pragma unroll
        for (int rb = 0; rb < 2; ++rb) {
          acc[rb][cb] = __builtin_amdgcn_mfma_f32_16x16x32_bf16(al2[rb], bh, acc[rb][cb], 0, 0, 0);
          acc[rb][cb] = __builtin_amdgcn_mfma_f32_16x16x32_bf16(ah[rb], bl, acc[rb][cb], 0, 0, 0);
          acc[rb][cb] = __builtin_amdgcn_mfma_f32_16x16x32_bf16(ah[rb], bh, acc[rb][cb], 0, 0, 0);
        }
      }
    }
  }
  unsigned short* H = (z == 0) ? qhh : khh;
  unsigned short* L = (z == 0) ? qhl : khl;
#pragma unroll
  for (int cb = 0; cb < 4; ++cb) {
    const int col = n0 + wc * 64 + cb * 16 + l15;
    const float bia = bias[col];
    const int h = col >> 6, d = col & 63;
#pragma unroll
    for (int rb = 0; rb < 2; ++rb)
#pragma unroll
      for (int ri = 0; ri < 4; ++ri) {
        const int row = r0 + wr * 32 + rb * 16 + l4 * 4 + ri;
        const int b = row >> 10, ll = row & 1023;
        const size_t idx = ((size_t)(h * 4 + b) << 16) + (ll << 6) + d;
        const float val = acc[rb][cb][ri] + bia;
        if (z == 2) {
          vh[idx] = val;
        } else {
          const unsigned short hv = f2bf(val);
          H[idx] = hv;
          L[idx] = f2bf(val - bf2f(hv));
        }
      }
  }
}

// ---------------- score tile helper (must be bit-identical in both passes) -
__device__ __forceinline__ f32x4 score_tile(
    const bf16x8* qh8, const bf16x8* ql8,
    const unsigned short* __restrict__ khh, const unsigned short* __restrict__ khl,
    size_t ka)
{
  const bf16x8 kh0 = *(const bf16x8*)(khh + ka);
  const bf16x8 kl0 = *(const bf16x8*)(khl + ka);
  const bf16x8 kh1 = *(const bf16x8*)(khh + ka + 32);
  const bf16x8 kl1 = *(const bf16x8*)(khl + ka + 32);
  f32x4 a0 = (f32x4){0.f, 0.f, 0.f, 0.f};
  f32x4 a1 = (f32x4){0.f, 0.f, 0.f, 0.f};
  a0 = __builtin_amdgcn_mfma_f32_16x16x32_bf16(ql8[0], kh0, a0, 0, 0, 0);
  a0 = __builtin_amdgcn_mfma_f32_16x16x32_bf16(qh8[0], kl0, a0, 0, 0, 0);
  a0 = __builtin_amdgcn_mfma_f32_16x16x32_bf16(qh8[0], kh0, a0, 0, 0, 0);
  a1 = __builtin_amdgcn_mfma_f32_16x16x32_bf16(ql8[1], kh1, a1, 0, 0, 0);
  a1 = __builtin_amdgcn_mfma_f32_16x16x32_bf16(qh8[1], kl1, a1, 0, 0, 0);
  a1 = __builtin_amdgcn_mfma_f32_16x16x32_bf16(qh8[1], kh1, a1, 0, 0, 0);
  return a0 + a1;
}

// ---------------- kernel 2: sparse attention, two-sweep, wave-independent --
// Block = 16 q-rows of one bh; 4 waves, wave w owns kv quarter [w*256,(w+1)*256).
// Pass 1 (no barriers): 16 tiles, 6 MFMA each, per-lane {Z-sum, top6 of raw
//   scores}. Merge intra-wave (butterfly) then cross-wave (LDS).
// Pass 2: recompute bit-identically; SCATTER only the <=5 survivors/row into
//   the pre-zeroed attn (the 128 MB bulk write is done by zerofill_kernel at
//   coalesced-fill rate); collect survivors, then PV + out_full split write.
__global__ __launch_bounds__(256) void sparse_attn_kernel(
    const unsigned short* __restrict__ qhh, const unsigned short* __restrict__ qhl,
    const unsigned short* __restrict__ khh, const unsigned short* __restrict__ khl,
    const float* __restrict__ vh, float* __restrict__ attn,
    unsigned short* __restrict__ ofhi, unsigned short* __restrict__ oflo)
{
  __shared__ float s_mrg[4][16][8];   // [wave][row][{Z, t0..t5, pad2}]
  __shared__ float s_sw[16][4][6];    // [row][quarter][slot]
  __shared__ int   s_si[16][4][6];
  __shared__ int   s_cnt[16][4];

  // XCD-aware swizzle: 4 bh per XCD so Q/K/V splits stay L2-resident
  const int bid = blockIdx.x;
  const int bh  = ((bid & 7) << 2) | ((bid >> 3) >> 6);
  const int rowbase = ((bid >> 3) & 63) << 4;

  const int tid = threadIdx.x, lane = tid & 63, wvid = tid >> 6;
  const int l15 = lane & 15, l4 = lane >> 4;
  const size_t base = (size_t)bh << 16;
  const int kvbase = wvid << 8;

  // Q fragments (16 rows, live through both passes)
  bf16x8 qh8[2], ql8[2];
#pragma unroll
  for (int kf = 0; kf < 2; ++kf) {
    const size_t qa = base + (size_t)(rowbase + l15) * 64 + kf * 32 + l4 * 8;
    qh8[kf] = *(const bf16x8*)(qhh + qa);
    ql8[kf] = *(const bf16x8*)(qhl + qa);
  }
  const size_t k0 = base + (size_t)(kvbase + l15) * 64 + l4 * 8;

  // ---- pass 1: Z-sum + top-6 of raw scores, per (lane, ri) ----
  float t[4][6];
  float Zs[4] = {0.f, 0.f, 0.f, 0.f};
#pragma unroll
  for (int ri = 0; ri < 4; ++ri)
#pragma unroll
    for (int j = 0; j < 6; ++j) t[ri][j] = -3e38f;

  for (int kt = 0; kt < 16; ++kt) {
    const f32x4 acc = score_tile(qh8, ql8, khh, khl, k0 + (size_t)kt * 1024);
#pragma unroll
    for (int ri = 0; ri < 4; ++ri) {
      const float s = acc[ri];
      Zs[ri] += exp2f(s * CEXP);
      float v = s;
#pragma unroll
      for (int j = 0; j < 6; ++j) {
        const float a = fmaxf(t[ri][j], v);
        v = fminf(t[ri][j], v);
        t[ri][j] = a;
      }
    }
  }

  // ---- intra-wave merge across the 16 row-lanes (offsets 1,2,4,8) ----
#pragma unroll
  for (int ri = 0; ri < 4; ++ri) {
#pragma unroll
    for (int off = 1; off < 16; off <<= 1) Zs[ri] += __shfl_xor(Zs[ri], off);
#pragma unroll
    for (int off = 1; off < 16; off <<= 1) {
      float b[6];
#pragma unroll
      for (int j = 0; j < 6; ++j) b[j] = __shfl_xor(t[ri][j], off);
      merge6(t[ri], b);
    }
  }

  // ---- cross-wave merge via LDS ----
  if (l15 < 7) {
#pragma unroll
    for (int ri = 0; ri < 4; ++ri) {
      const float val = (l15 == 0) ? Zs[ri] :
                        (l15 == 1) ? t[ri][0] : (l15 == 2) ? t[ri][1] :
                        (l15 == 3) ? t[ri][2] : (l15 == 4) ? t[ri][3] :
                        (l15 == 5) ? t[ri][4] : t[ri][5];
      s_mrg[wvid][l4 * 4 + ri][l15] = val;
    }
  }
  __syncthreads();

  float u6x[4], inv[4];
#pragma unroll
  for (int ri = 0; ri < 4; ++ri) {
    const int row = l4 * 4 + ri;
    float m[6], Zt = 0.f;
#pragma unroll
    for (int w2 = 0; w2 < 4; ++w2) {
      const f32x4 pa = *(const f32x4*)&s_mrg[w2][row][0];
      const f32x4 pb = *(const f32x4*)&s_mrg[w2][row][4];
      Zt += pa[0];
      float b[6] = {pa[1], pa[2], pa[3], pb[0], pb[1], pb[2]};
      if (w2 == 0) {
#pragma unroll
        for (int j = 0; j < 6; ++j) m[j] = b[j];
      } else {
        merge6(m, b);
      }
    }
    const float Zx = SP_EPS * Zt;
    const float u6e = exp2f(m[5] * CEXP) + Zx;
    float Ss = 0.f;
    Ss += fmaxf(exp2f(m[0] * CEXP) - u6e, 0.f);
    Ss += fmaxf(exp2f(m[1] * CEXP) - u6e, 0.f);
    Ss += fmaxf(exp2f(m[2] * CEXP) - u6e, 0.f);
    Ss += fmaxf(exp2f(m[3] * CEXP) - u6e, 0.f);
    Ss += fmaxf(exp2f(m[4] * CEXP) - u6e, 0.f);
    u6x[ri] = u6e;
    inv[ri] = 1.0f / (Ss + Zx);
  }

  // ---- pass 2: recompute, survivor scatter (attn pre-zeroed) ----
  int cnt[4] = {0, 0, 0, 0};
  float* arow = attn + ((size_t)bh << 20);
  for (int kt = 0; kt < 16; ++kt) {
    const f32x4 acc = score_tile(qh8, ql8, khh, khl, k0 + (size_t)kt * 1024);
    const int kvi = kvbase + kt * 16 + l15;
#pragma unroll
    for (int ri = 0; ri < 4; ++ri) {
      const float u = exp2f(acc[ri] * CEXP);
      const float wv = u - u6x[ri];
      const unsigned long long msk = __ballot(wv > 0.f);
      const unsigned sub = (unsigned)(msk >> (l4 * 16)) & 0xFFFFu;
      if (wv > 0.f) {
        const float aval = wv * inv[ri];
        arow[(size_t)(rowbase + l4 * 4 + ri) * 1024 + kvi] = aval;
        const int pos = cnt[ri] + __popc(sub & ((1u << l15) - 1u));
        if (pos < 6) {
          s_sw[l4 * 4 + ri][wvid][pos] = aval;
          s_si[l4 * 4 + ri][wvid][pos] = kvi;
        }
      }
      cnt[ri] += __popc(sub);
    }
  }
  if (l15 == 0) {
#pragma unroll
    for (int ri = 0; ri < 4; ++ri) s_cnt[l4 * 4 + ri][wvid] = min(cnt[ri], 6);
  }
  __syncthreads();

  // ---- PV + out_full split write: wave w handles rows 4w..4w+3, lane=dim --
  const float* vb = vh + base;
  const int b_ = bh & 3, h = bh >> 2;
#pragma unroll
  for (int rr = 0; rr < 4; ++rr) {
    const int row = (wvid << 2) | rr;
    float a = 0.f;
#pragma unroll
    for (int qw = 0; qw < 4; ++qw) {
      const int n = s_cnt[row][qw];
      for (int tt = 0; tt < n; ++tt)
        a = fmaf(s_sw[row][qw][tt], vb[(size_t)s_si[row][qw][tt] * 64 + lane], a);
    }
    const int lq = rowbase + row;
    const int oidx = (((b_ << 10) | lq) << 9) + (h << 6) + lane;
    const unsigned short hv = f2bf(a);
    ofhi[oidx] = hv;
    oflo[oidx] = f2bf(a - bf2f(hv));
  }
}

// ---------------- kernel 3: fc+gate via split-bf16 MFMA + fused epilogue ---
__global__ __launch_bounds__(256) void out_proj_mfma_kernel(
    const unsigned short* __restrict__ ofhi, const unsigned short* __restrict__ oflo,
    const unsigned short* __restrict__ FG,
    const float* __restrict__ bfc, const float* __restrict__ bg,
    float* __restrict__ out)
{
  __shared__ short Ash[64 * 64], Asl[64 * 64];
  __shared__ short Bfh[128 * 64], Bfl[128 * 64];
  __shared__ short Bgh[128 * 64], Bgl[128 * 64];
  const unsigned short* Wfh = FG;
  const unsigned short* Wfl = FG + (1u << 18);
  const unsigned short* Wgh = FG + (2u << 18);
  const unsigned short* Wgl = FG + 3u * (1u << 18);
  const int r0 = blockIdx.x * 64, n0 = blockIdx.y * 128;
  const int tid = threadIdx.x, lane = tid & 63, w = tid >> 6;
  const int wr = w >> 1, wc = w & 1;
  const int l15 = lane & 15, l4 = lane >> 4;

  f32x4 accf[2][4], accg[2][4];
#pragma unroll
  for (int a = 0; a < 2; ++a)
#pragma unroll
    for (int b = 0; b < 4; ++b) {
      accf[a][b] = (f32x4){0.f, 0.f, 0.f, 0.f};
      accg[a][b] = (f32x4){0.f, 0.f, 0.f, 0.f};
    }

  for (int kt = 0; kt < 8; ++kt) {
    __syncthreads();
#pragma unroll
    for (int p = 0; p < 2; ++p) {
      const int c = tid + p * 256, row = c >> 3, k8 = (c & 7) * 8;
      const size_t go = (size_t)(r0 + row) * 512 + kt * 64 + k8;
      const int si = row * 64 + (k8 ^ ((row & 7) << 3));
      *(bf16x8*)&Ash[si] = *(const bf16x8*)(ofhi + go);
      *(bf16x8*)&Asl[si] = *(const bf16x8*)(oflo + go);
    }
#pragma unroll
    for (int p = 0; p < 4; ++p) {
      const int c = tid + p * 256, row = c >> 3, k8 = (c & 7) * 8;
      const int si = row * 64 + (k8 ^ ((row & 7) << 3));
      const size_t go = (size_t)(n0 + row) * 512 + kt * 64 + k8;
      *(bf16x8*)&Bfh[si] = *(const bf16x8*)(Wfh + go);
      *(bf16x8*)&Bfl[si] = *(const bf16x8*)(Wfl + go);
      *(bf16x8*)&Bgh[si] = *(const bf16x8*)(Wgh + go);
      *(bf16x8*)&Bgl[si] = *(const bf16x8*)(Wgl + go);
    }
    __syncthreads();
#pragma unroll
    for (int kf = 0; kf < 2; ++kf) {
      const int kb = kf * 32 + l4 * 8;
      bf16x8 ah[2], al2[2];
#pragma unroll
      for (int rb = 0; rb < 2; ++rb) {
        const int ar = wr * 32 + rb * 16 + l15;
        const int si = ar * 64 + (kb ^ ((ar & 7) << 3));
        ah[rb] = *(bf16x8*)&Ash[si]; al2[rb] = *(bf16x8*)&Asl[si];
      }
#pragma unroll
      for (int cb = 0; cb < 4; ++cb) {
        const int br = wc * 64 + cb * 16 + l15;
        const int si = br * 64 + (kb ^ ((br & 7) << 3));
        const bf16x8 fh = *(bf16x8*)&Bfh[si];
        const bf16x8 fl = *(bf16x8*)&Bfl[si];
        const bf16x8 gh = *(bf16x8*)&Bgh[si];
        const bf16x8 gl = *(bf16x8*)&Bgl[si];
#pragma unroll
        for (int rb = 0; rb < 2; ++rb) {
          accf[rb][cb] = __builtin_amdgcn_mfma_f32_16x16x32_bf16(al2[rb], fh, accf[rb][cb], 0, 0, 0);
          accf[rb][cb] = __builtin_amdgcn_mfma_f32_16x16x32_bf16(ah[rb], fl, accf[rb][cb], 0, 0, 0);
          accf[rb][cb] = __builtin_amdgcn_mfma_f32_16x16x32_bf16(ah[rb], fh, accf[rb][cb], 0, 0, 0);
          accg[rb][cb] = __builtin_amdgcn_mfma_f32_16x16x32_bf16(al2[rb], gh, accg[rb][cb], 0, 0, 0);
          accg[rb][cb] = __builtin_amdgcn_mfma_f32_16x16x32_bf16(ah[rb], gl, accg[rb][cb], 0, 0, 0);
          accg[rb][cb] = __builtin_amdgcn_mfma_f32_16x16x32_bf16(ah[rb], gh, accg[rb][cb], 0, 0, 0);
        }
      }
    }
  }
#pragma unroll
  for (int cb = 0; cb < 4; ++cb) {
    const int col = n0 + wc * 64 + cb * 16 + l15;
    const float bf4 = bfc[col];
    const float bg4 = bg[col];
#pragma unroll
    for (int rb = 0; rb < 2; ++rb)
#pragma unroll
      for (int ri = 0; ri < 4; ++ri) {
        const int row = r0 + wr * 32 + rb * 16 + l4 * 4 + ri;
        const float f = accf[rb][cb][ri] + bf4;
        const float g = accg[rb][cb][ri] + bg4;
        out[(size_t)row * 512 + col] = tanhf(f) / (1.f + __expf(-g));
      }
  }
}

extern "C" void kernel_launch(void* const* d_in, const int* in_sizes, int n_in,
                              void* d_out, int out_size, void* d_ws, size_t ws_size,
                              hipStream_t stream) {
  const float* q   = (const float*)d_in[0];
  const float* k   = (const float*)d_in[1];
  const float* v   = (const float*)d_in[2];
  const float* Wq  = (const float*)d_in[3];
  const float* bq  = (const float*)d_in[4];
  const float* Wk  = (const float*)d_in[5];
  const float* bk  = (const float*)d_in[6];
  const float* Wv  = (const float*)d_in[7];
  const float* bv  = (const float*)d_in[8];
  const float* Wfc = (const float*)d_in[9];
  const float* bfc = (const float*)d_in[10];
  const float* Wg  = (const float*)d_in[11];
  const float* bg  = (const float*)d_in[12];

  float* out  = (float*)d_out;
  float* attn = out + OUT0;                 // (32,1024,1024) final output 1

  // qh splits live in the out0 region (8MB, overwritten by out_proj at the end)
  unsigned short* qhh = (unsigned short*)d_out;
  unsigned short* qhl = qhh + (1u << 21);

  // ws (24MB): [0,8M) khh/khl -> later FG; [8,16M) vh; [16M..) Wqkv -> ofhi/oflo
  char* wsb = (char*)d_ws;
  unsigned short* khh  = (unsigned short*)wsb;
  unsigned short* khl  = (unsigned short*)(wsb + (4u << 20));
  float*          vh   = (float*)(wsb + (8u << 20));
  unsigned short* Wqkv = (unsigned short*)(wsb + (16u << 20));
  unsigned short* ofhi = (unsigned short*)(wsb + (16u << 20));
  unsigned short* oflo = (unsigned short*)(wsb + (20u << 20));
  unsigned short* FG   = (unsigned short*)wsb;

  zerofill_kernel<<<dim3(2048), 256, 0, stream>>>((float4*)attn, 1 << 23);
  convW_kernel<<<dim3(256, 1, 3), 256, 0, stream>>>(Wq, Wk, Wv, Wqkv);
  qkv_mfma_kernel<<<dim3(64, 4, 3), 256, 0, stream>>>(q, k, v, Wqkv, bq, bk, bv,
                                                      qhh, qhl, khh, khl, vh);
  sparse_attn_kernel<<<dim3(2048), 256, 0, stream>>>(qhh, qhl, khh, khl, vh,
                                                     attn, ofhi, oflo);
  convW_kernel<<<dim3(256, 1, 2), 256, 0, stream>>>(Wfc, Wg, Wg, FG);
  out_proj_mfma_kernel<<<dim3(64, 4), 256, 0, stream>>>(ofhi, oflo, FG, bfc, bg, out);
}

// Round 10
// 175.632 us; speedup vs baseline: 1.2113x; 1.2113x over previous
//
#include <hip/hip_runtime.h>
#include <hip/hip_bf16.h>
#include <math.h>

#define OUT0   2097152      // 4*1024*512 (output 0 size)
#define SP_EPS 1e-7f
#define CEXP   0.18033688011112042f   // 0.125 * log2(e): exp(s/8) == exp2(s*CEXP)

typedef __attribute__((ext_vector_type(8))) short bf16x8;
typedef __attribute__((ext_vector_type(4))) float f32x4;

// ---------------- bf16 split helpers (RN-to-nearest-even) ------------------
__device__ __forceinline__ unsigned short f2bf(float f) {
  unsigned int b = __float_as_uint(f);
  return (unsigned short)((b + 0x7fffu + ((b >> 16) & 1u)) >> 16);
}
__device__ __forceinline__ float bf2f(unsigned short u) {
  return __uint_as_float(((unsigned int)u) << 16);
}

// merge two sorted-desc 6-lists -> top-6 of union, sorted desc, into a[]
__device__ __forceinline__ void merge6(float a[6], const float b[6]) {
  float m0 = fmaxf(a[0], b[5]), m1 = fmaxf(a[1], b[4]), m2 = fmaxf(a[2], b[3]),
        m3 = fmaxf(a[3], b[2]), m4 = fmaxf(a[4], b[1]), m5 = fmaxf(a[5], b[0]);
  float x;
  x = fmaxf(m0, m3); m3 = fminf(m0, m3); m0 = x;
  x = fmaxf(m1, m4); m4 = fminf(m1, m4); m1 = x;
  x = fmaxf(m2, m5); m5 = fminf(m2, m5); m2 = x;
  x = fmaxf(m0, m1); m1 = fminf(m0, m1); m0 = x;
  x = fmaxf(m0, m2); m2 = fminf(m0, m2); m0 = x;
  x = fmaxf(m1, m2); m2 = fminf(m1, m2); m1 = x;
  x = fmaxf(m3, m4); m4 = fminf(m3, m4); m3 = x;
  x = fmaxf(m3, m5); m5 = fminf(m3, m5); m3 = x;
  x = fmaxf(m4, m5); m5 = fminf(m4, m5); m4 = x;
  a[0] = m0; a[1] = m1; a[2] = m2; a[3] = m3; a[4] = m4; a[5] = m5;
}

// ---------------- kernel Z: zero-fill the attn region (128 MB) -------------
__global__ __launch_bounds__(256) void zerofill_kernel(float4* __restrict__ p, int n4) {
  const int stride = gridDim.x * 256;
  for (int i = blockIdx.x * 256 + threadIdx.x; i < n4; i += stride)
    p[i] = make_float4(0.f, 0.f, 0.f, 0.f);
}

// ---------------- kernel 0: split-convert up to 3 weight matrices ----------
__global__ __launch_bounds__(256) void convW_kernel(
    const float* __restrict__ w0, const float* __restrict__ w1,
    const float* __restrict__ w2, unsigned short* __restrict__ dst)
{
  const int z = blockIdx.z;
  const float* src = (z == 0) ? w0 : (z == 1) ? w1 : w2;
  unsigned short* hi = dst + (size_t)z * (1u << 19);
  unsigned short* lo = hi + (1u << 18);
  const int i = (blockIdx.x * 256 + threadIdx.x) * 4;
  const float4 x = *(const float4*)(src + i);
  ushort4 h, l;
  h.x = f2bf(x.x); l.x = f2bf(x.x - bf2f(h.x));
  h.y = f2bf(x.y); l.y = f2bf(x.y - bf2f(h.y));
  h.z = f2bf(x.z); l.z = f2bf(x.z - bf2f(h.z));
  h.w = f2bf(x.w); l.w = f2bf(x.w - bf2f(h.w));
  *(ushort4*)(hi + i) = h;
  *(ushort4*)(lo + i) = l;
}

// ---------------- kernel 1: QKV projection via split-bf16 MFMA -------------
__global__ __launch_bounds__(256) void qkv_mfma_kernel(
    const float* __restrict__ q, const float* __restrict__ k, const float* __restrict__ v,
    const unsigned short* __restrict__ Wsplit,
    const float* __restrict__ bq, const float* __restrict__ bk, const float* __restrict__ bv,
    unsigned short* __restrict__ qhh, unsigned short* __restrict__ qhl,
    unsigned short* __restrict__ khh, unsigned short* __restrict__ khl,
    float* __restrict__ vh)
{
  __shared__ short Ash[64 * 64], Asl[64 * 64];
  __shared__ short Bsh[128 * 64], Bsl[128 * 64];
  const int z = blockIdx.z;
  const float* A = (z == 0) ? q : (z == 1) ? k : v;
  const unsigned short* Wh = Wsplit + (size_t)z * (1u << 19);
  const unsigned short* Wl = Wh + (1u << 18);
  const float* bias = (z == 0) ? bq : (z == 1) ? bk : bv;
  const int r0 = blockIdx.x * 64, n0 = blockIdx.y * 128;
  const int tid = threadIdx.x, lane = tid & 63, w = tid >> 6;
  const int wr = w >> 1, wc = w & 1;
  const int l15 = lane & 15, l4 = lane >> 4;

  f32x4 acc[2][4];
#pragma unroll
  for (int a = 0; a < 2; ++a)
#pragma unroll
    for (int b = 0; b < 4; ++b) acc[a][b] = (f32x4){0.f, 0.f, 0.f, 0.f};

  for (int kt = 0; kt < 8; ++kt) {
    __syncthreads();
#pragma unroll
    for (int p = 0; p < 2; ++p) {
      const int c = tid + p * 256, row = c >> 3, k8 = (c & 7) * 8;
      const float4 x0 = *(const float4*)(A + (size_t)(r0 + row) * 512 + kt * 64 + k8);
      const float4 x1 = *(const float4*)(A + (size_t)(r0 + row) * 512 + kt * 64 + k8 + 4);
      bf16x8 hv, lv;
      const float xs[8] = {x0.x, x0.y, x0.z, x0.w, x1.x, x1.y, x1.z, x1.w};
#pragma unroll
      for (int j = 0; j < 8; ++j) {
        const unsigned short h = f2bf(xs[j]);
        hv[j] = (short)h; lv[j] = (short)f2bf(xs[j] - bf2f(h));
      }
      const int si = row * 64 + (k8 ^ ((row & 7) << 3));
      *(bf16x8*)&Ash[si] = hv; *(bf16x8*)&Asl[si] = lv;
    }
#pragma unroll
    for (int p = 0; p < 4; ++p) {
      const int c = tid + p * 256, row = c >> 3, k8 = (c & 7) * 8;
      const size_t go = (size_t)(n0 + row) * 512 + kt * 64 + k8;
      const int si = row * 64 + (k8 ^ ((row & 7) << 3));
      *(bf16x8*)&Bsh[si] = *(const bf16x8*)(Wh + go);
      *(bf16x8*)&Bsl[si] = *(const bf16x8*)(Wl + go);
    }
    __syncthreads();
#pragma unroll
    for (int kf = 0; kf < 2; ++kf) {
      const int kb = kf * 32 + l4 * 8;
      bf16x8 ah[2], al2[2];
#pragma unroll
      for (int rb = 0; rb < 2; ++rb) {
        const int ar = wr * 32 + rb * 16 + l15;
        const int si = ar * 64 + (kb ^ ((ar & 7) << 3));
        ah[rb] = *(bf16x8*)&Ash[si]; al2[rb] = *(bf16x8*)&Asl[si];
      }
#pragma unroll
      for (int cb = 0; cb < 4; ++cb) {
        const int br = wc * 64 + cb * 16 + l15;
        const int si = br * 64 + (kb ^ ((br & 7) << 3));
        const bf16x8 bh = *(bf16x8*)&Bsh[si];
        const bf16x8 bl = *(bf16x8*)&Bsl[si];
#pragma unroll
        for (int rb = 0; rb < 2; ++rb) {
          acc[rb][cb] = __builtin_amdgcn_mfma_f32_16x16x32_bf16(al2[rb], bh, acc[rb][cb], 0, 0, 0);
          acc[rb][cb] = __builtin_amdgcn_mfma_f32_16x16x32_bf16(ah[rb], bl, acc[rb][cb], 0, 0, 0);
          acc[rb][cb] = __builtin_amdgcn_mfma_f32_16x16x32_bf16(ah[rb], bh, acc[rb][cb], 0, 0, 0);
        }
      }
    }
  }
  unsigned short* H = (z == 0) ? qhh : khh;
  unsigned short* L = (z == 0) ? qhl : khl;
#pragma unroll
  for (int cb = 0; cb < 4; ++cb) {
    const int col = n0 + wc * 64 + cb * 16 + l15;
    const float bia = bias[col];
    const int h = col >> 6, d = col & 63;
#pragma unroll
    for (int rb = 0; rb < 2; ++rb)
#pragma unroll
      for (int ri = 0; ri < 4; ++ri) {
        const int row = r0 + wr * 32 + rb * 16 + l4 * 4 + ri;
        const int b = row >> 10, ll = row & 1023;
        const size_t idx = ((size_t)(h * 4 + b) << 16) + (ll << 6) + d;
        const float val = acc[rb][cb][ri] + bia;
        if (z == 2) {
          vh[idx] = val;
        } else {
          const unsigned short hv = f2bf(val);
          H[idx] = hv;
          L[idx] = f2bf(val - bf2f(hv));
        }
      }
  }
}

// ---------------- kernel 2: one-sweep fused sparse attention ---------------
// Block = 16 q-rows of one bh, 8 waves (512 thr). Wave w computes cols
// [w*128,(w+1)*128) scores via split-bf16 MFMA and KEEPS them in registers
// (sc[8] f32x4). Per-lane {Z, top6 of raw scores} -> 16-lane butterfly ->
// LDS partials -> wave-0 merge (u6x, inv) -> every lane rescans its register
// scores with the SAME exp2 form, scatters <=5 survivors/row into pre-zeroed
// attn, collects them deterministically, then PV + out_full hi/lo write.
__global__ __launch_bounds__(512) void fused_attn_kernel(
    const unsigned short* __restrict__ qhh, const unsigned short* __restrict__ qhl,
    const unsigned short* __restrict__ khh, const unsigned short* __restrict__ khl,
    const float* __restrict__ vh, float* __restrict__ attn,
    unsigned short* __restrict__ ofhi, unsigned short* __restrict__ oflo)
{
  __shared__ float s_part[8][16][8];   // [wave][row][{Z, t0..t5, pad}]
  __shared__ float s_fin[16][2];       // [row][{u6x, inv}]
  __shared__ float s_sw[16][8][6];     // survivor weights [row][wave][slot]
  __shared__ int   s_si[16][8][6];     // survivor kv indices
  __shared__ int   s_cnt[16][8];

  // XCD-aware swizzle: 4 bh per XCD so each XCD's Q/K/V stay L2-resident
  const int bid = blockIdx.x;
  const int bh  = ((bid & 7) << 2) | (bid >> 9);
  const int rowbase = ((bid >> 3) & 63) << 4;
  const int tid = threadIdx.x, lane = tid & 63, wvid = tid >> 6;
  const int l15 = lane & 15, l4 = lane >> 4;
  const size_t base = (size_t)bh << 16;

  // Q fragments for the block's 16 rows (identical in all waves; L2 broadcast)
  bf16x8 qh8[2], ql8[2];
#pragma unroll
  for (int kf = 0; kf < 2; ++kf) {
    const size_t qa = base + (size_t)(rowbase + l15) * 64 + kf * 32 + l4 * 8;
    qh8[kf] = *(const bf16x8*)(qhh + qa);
    ql8[kf] = *(const bf16x8*)(qhl + qa);
  }

  // ---- phase A: 8 score tiles, kept in registers ----
  f32x4 sc[8];
#pragma unroll
  for (int cb = 0; cb < 8; ++cb) {
    const size_t kr = base + (size_t)(wvid * 128 + cb * 16 + l15) * 64 + l4 * 8;
    const bf16x8 kh0 = *(const bf16x8*)(khh + kr);
    const bf16x8 kl0 = *(const bf16x8*)(khl + kr);
    const bf16x8 kh1 = *(const bf16x8*)(khh + kr + 32);
    const bf16x8 kl1 = *(const bf16x8*)(khl + kr + 32);
    f32x4 a0 = (f32x4){0.f, 0.f, 0.f, 0.f};
    f32x4 a1 = (f32x4){0.f, 0.f, 0.f, 0.f};
    a0 = __builtin_amdgcn_mfma_f32_16x16x32_bf16(ql8[0], kh0, a0, 0, 0, 0);
    a0 = __builtin_amdgcn_mfma_f32_16x16x32_bf16(qh8[0], kl0, a0, 0, 0, 0);
    a0 = __builtin_amdgcn_mfma_f32_16x16x32_bf16(qh8[0], kh0, a0, 0, 0, 0);
    a1 = __builtin_amdgcn_mfma_f32_16x16x32_bf16(ql8[1], kh1, a1, 0, 0, 0);
    a1 = __builtin_amdgcn_mfma_f32_16x16x32_bf16(qh8[1], kl1, a1, 0, 0, 0);
    a1 = __builtin_amdgcn_mfma_f32_16x16x32_bf16(qh8[1], kh1, a1, 0, 0, 0);
    sc[cb] = a0 + a1;
  }

  // ---- per-lane stats: Z-sum + top-6 of raw scores ----
  float t[4][6];
  float Zs[4] = {0.f, 0.f, 0.f, 0.f};
#pragma unroll
  for (int ri = 0; ri < 4; ++ri)
#pragma unroll
    for (int j = 0; j < 6; ++j) t[ri][j] = -3e38f;
#pragma unroll
  for (int cb = 0; cb < 8; ++cb)
#pragma unroll
    for (int ri = 0; ri < 4; ++ri) {
      const float s = sc[cb][ri];
      Zs[ri] += exp2f(s * CEXP);
      float v = s;
#pragma unroll
      for (int j = 0; j < 6; ++j) {
        const float a = fmaxf(t[ri][j], v);
        v = fminf(t[ri][j], v);
        t[ri][j] = a;
      }
    }

  // ---- butterfly merge across the 16 row-lanes ----
#pragma unroll
  for (int ri = 0; ri < 4; ++ri) {
#pragma unroll
    for (int off = 1; off < 16; off <<= 1) Zs[ri] += __shfl_xor(Zs[ri], off);
#pragma unroll
    for (int off = 1; off < 16; off <<= 1) {
      float b[6];
#pragma unroll
      for (int j = 0; j < 6; ++j) b[j] = __shfl_xor(t[ri][j], off);
      merge6(t[ri], b);
    }
  }

  // ---- write per-(wave,row) partials ----
  if (l15 < 7) {
#pragma unroll
    for (int ri = 0; ri < 4; ++ri) {
      const float val = (l15 == 0) ? Zs[ri] :
                        (l15 == 1) ? t[ri][0] : (l15 == 2) ? t[ri][1] :
                        (l15 == 3) ? t[ri][2] : (l15 == 4) ? t[ri][3] :
                        (l15 == 5) ? t[ri][4] : t[ri][5];
      s_part[wvid][l4 * 4 + ri][l15] = val;
    }
  }
  __syncthreads();

  // ---- wave 0: merge 8 strips per row -> u6x, inv ----
  if (tid < 16) {
    float m[6];
    float Zt = 0.f;
#pragma unroll
    for (int w2 = 0; w2 < 8; ++w2) {
      Zt += s_part[w2][tid][0];
      float b[6] = {s_part[w2][tid][1], s_part[w2][tid][2], s_part[w2][tid][3],
                    s_part[w2][tid][4], s_part[w2][tid][5], s_part[w2][tid][6]};
      if (w2 == 0) {
#pragma unroll
        for (int j = 0; j < 6; ++j) m[j] = b[j];
      } else {
        merge6(m, b);
      }
    }
    const float Zx = SP_EPS * Zt;
    const float u6e = exp2f(m[5] * CEXP) + Zx;
    float Ss = 0.f;
    Ss += fmaxf(exp2f(m[0] * CEXP) - u6e, 0.f);
    Ss += fmaxf(exp2f(m[1] * CEXP) - u6e, 0.f);
    Ss += fmaxf(exp2f(m[2] * CEXP) - u6e, 0.f);
    Ss += fmaxf(exp2f(m[3] * CEXP) - u6e, 0.f);
    Ss += fmaxf(exp2f(m[4] * CEXP) - u6e, 0.f);
    s_fin[tid][0] = u6e;
    s_fin[tid][1] = 1.0f / (Ss + Zx);
  }
  __syncthreads();

  // ---- rescan register scores: scatter survivors + collect ----
  float u6xr[4], invr[4];
#pragma unroll
  for (int ri = 0; ri < 4; ++ri) {
    u6xr[ri] = s_fin[l4 * 4 + ri][0];
    invr[ri] = s_fin[l4 * 4 + ri][1];
  }
  int cnt[4] = {0, 0, 0, 0};
#pragma unroll
  for (int cb = 0; cb < 8; ++cb)
#pragma unroll
    for (int ri = 0; ri < 4; ++ri) {
      const float u = exp2f(sc[cb][ri] * CEXP);
      const float wv = u - u6xr[ri];
      const unsigned long long msk = __ballot(wv > 0.f);
      const unsigned sub = (unsigned)(msk >> (l4 * 16)) & 0xFFFFu;
      if (wv > 0.f) {
        const int row = l4 * 4 + ri;
        const int kvi = wvid * 128 + cb * 16 + l15;
        const float aval = wv * invr[ri];
        attn[((size_t)bh << 20) + (size_t)(rowbase + row) * 1024 + kvi] = aval;
        const int pos = cnt[ri] + __popc(sub & ((1u << l15) - 1u));
        if (pos < 6) {
          s_sw[row][wvid][pos] = aval;
          s_si[row][wvid][pos] = kvi;
        }
      }
      cnt[ri] += __popc(sub);
    }
  if (l15 == 0) {
#pragma unroll
    for (int ri = 0; ri < 4; ++ri) s_cnt[l4 * 4 + ri][wvid] = min(cnt[ri], 6);
  }
  __syncthreads();

  // ---- PV + out_full split write: 2 rows per wave, lane = dim ----
  const float* vb = vh + base;
  const int b_ = bh & 3, h = bh >> 2;
#pragma unroll
  for (int rr = 0; rr < 2; ++rr) {
    const int row = (wvid << 1) | rr;
    float a = 0.f;
#pragma unroll
    for (int w2 = 0; w2 < 8; ++w2) {
      const int n = s_cnt[row][w2];
      for (int tt = 0; tt < n; ++tt)
        a = fmaf(s_sw[row][w2][tt], vb[(size_t)s_si[row][w2][tt] * 64 + lane], a);
    }
    const int lq = rowbase + row;
    const int oidx = (((b_ << 10) | lq) << 9) + (h << 6) + lane;
    const unsigned short hv = f2bf(a);
    ofhi[oidx] = hv;
    oflo[oidx] = f2bf(a - bf2f(hv));
  }
}

// ---------------- kernel 3: fc+gate via split-bf16 MFMA + fused epilogue ---
__global__ __launch_bounds__(256) void out_proj_mfma_kernel(
    const unsigned short* __restrict__ ofhi, const unsigned short* __restrict__ oflo,
    const unsigned short* __restrict__ FG,
    const float* __restrict__ bfc, const float* __restrict__ bg,
    float* __restrict__ out)
{
  __shared__ short Ash[64 * 64], Asl[64 * 64];
  __shared__ short Bfh[128 * 64], Bfl[128 * 64];
  __shared__ short Bgh[128 * 64], Bgl[128 * 64];
  const unsigned short* Wfh = FG;
  const unsigned short* Wfl = FG + (1u << 18);
  const unsigned short* Wgh = FG + (2u << 18);
  const unsigned short* Wgl = FG + 3u * (1u << 18);
  const int r0 = blockIdx.x * 64, n0 = blockIdx.y * 128;
  const int tid = threadIdx.x, lane = tid & 63, w = tid >> 6;
  const int wr = w >> 1, wc = w & 1;
  const int l15 = lane & 15, l4 = lane >> 4;

  f32x4 accf[2][4], accg[2][4];
#pragma unroll
  for (int a = 0; a < 2; ++a)
#pragma unroll
    for (int b = 0; b < 4; ++b) {
      accf[a][b] = (f32x4){0.f, 0.f, 0.f, 0.f};
      accg[a][b] = (f32x4){0.f, 0.f, 0.f, 0.f};
    }

  for (int kt = 0; kt < 8; ++kt) {
    __syncthreads();
#pragma unroll
    for (int p = 0; p < 2; ++p) {
      const int c = tid + p * 256, row = c >> 3, k8 = (c & 7) * 8;
      const size_t go = (size_t)(r0 + row) * 512 + kt * 64 + k8;
      const int si = row * 64 + (k8 ^ ((row & 7) << 3));
      *(bf16x8*)&Ash[si] = *(const bf16x8*)(ofhi + go);
      *(bf16x8*)&Asl[si] = *(const bf16x8*)(oflo + go);
    }
#pragma unroll
    for (int p = 0; p < 4; ++p) {
      const int c = tid + p * 256, row = c >> 3, k8 = (c & 7) * 8;
      const int si = row * 64 + (k8 ^ ((row & 7) << 3));
      const size_t go = (size_t)(n0 + row) * 512 + kt * 64 + k8;
      *(bf16x8*)&Bfh[si] = *(const bf16x8*)(Wfh + go);
      *(bf16x8*)&Bfl[si] = *(const bf16x8*)(Wfl + go);
      *(bf16x8*)&Bgh[si] = *(const bf16x8*)(Wgh + go);
      *(bf16x8*)&Bgl[si] = *(const bf16x8*)(Wgl + go);
    }
    __syncthreads();
#pragma unroll
    for (int kf = 0; kf < 2; ++kf) {
      const int kb = kf * 32 + l4 * 8;
      bf16x8 ah[2], al2[2];
#pragma unroll
      for (int rb = 0; rb < 2; ++rb) {
        const int ar = wr * 32 + rb * 16 + l15;
        const int si = ar * 64 + (kb ^ ((ar & 7) << 3));
        ah[rb] = *(bf16x8*)&Ash[si]; al2[rb] = *(bf16x8*)&Asl[si];
      }
#pragma unroll
      for (int cb = 0; cb < 4; ++cb) {
        const int br = wc * 64 + cb * 16 + l15;
        const int si = br * 64 + (kb ^ ((br & 7) << 3));
        const bf16x8 fh = *(bf16x8*)&Bfh[si];
        const bf16x8 fl = *(bf16x8*)&Bfl[si];
        const bf16x8 gh = *(bf16x8*)&Bgh[si];
        const bf16x8 gl = *(bf16x8*)&Bgl[si];
#pragma unroll
        for (int rb = 0; rb < 2; ++rb) {
          accf[rb][cb] = __builtin_amdgcn_mfma_f32_16x16x32_bf16(al2[rb], fh, accf[rb][cb], 0, 0, 0);
          accf[rb][cb] = __builtin_amdgcn_mfma_f32_16x16x32_bf16(ah[rb], fl, accf[rb][cb], 0, 0, 0);
          accf[rb][cb] = __builtin_amdgcn_mfma_f32_16x16x32_bf16(ah[rb], fh, accf[rb][cb], 0, 0, 0);
          accg[rb][cb] = __builtin_amdgcn_mfma_f32_16x16x32_bf16(al2[rb], gh, accg[rb][cb], 0, 0, 0);
          accg[rb][cb] = __builtin_amdgcn_mfma_f32_16x16x32_bf16(ah[rb], gl, accg[rb][cb], 0, 0, 0);
          accg[rb][cb] = __builtin_amdgcn_mfma_f32_16x16x32_bf16(ah[rb], gh, accg[rb][cb], 0, 0, 0);
        }
      }
    }
  }
#pragma unroll
  for (int cb = 0; cb < 4; ++cb) {
    const int col = n0 + wc * 64 + cb * 16 + l15;
    const float bf4 = bfc[col];
    const float bg4 = bg[col];
#pragma unroll
    for (int rb = 0; rb < 2; ++rb)
#pragma unroll
      for (int ri = 0; ri < 4; ++ri) {
        const int row = r0 + wr * 32 + rb * 16 + l4 * 4 + ri;
        const float f = accf[rb][cb][ri] + bf4;
        const float g = accg[rb][cb][ri] + bg4;
        out[(size_t)row * 512 + col] = tanhf(f) / (1.f + __expf(-g));
      }
  }
}

extern "C" void kernel_launch(void* const* d_in, const int* in_sizes, int n_in,
                              void* d_out, int out_size, void* d_ws, size_t ws_size,
                              hipStream_t stream) {
  const float* q   = (const float*)d_in[0];
  const float* k   = (const float*)d_in[1];
  const float* v   = (const float*)d_in[2];
  const float* Wq  = (const float*)d_in[3];
  const float* bq  = (const float*)d_in[4];
  const float* Wk  = (const float*)d_in[5];
  const float* bk  = (const float*)d_in[6];
  const float* Wv  = (const float*)d_in[7];
  const float* bv  = (const float*)d_in[8];
  const float* Wfc = (const float*)d_in[9];
  const float* bfc = (const float*)d_in[10];
  const float* Wg  = (const float*)d_in[11];
  const float* bg  = (const float*)d_in[12];

  float* out  = (float*)d_out;
  float* attn = out + OUT0;                 // (32,1024,1024) final output 1

  // qh splits live in the out0 region (8MB, overwritten by out_proj at the end)
  unsigned short* qhh = (unsigned short*)d_out;
  unsigned short* qhl = qhh + (1u << 21);

  // ws (24MB): [0,8M) khh/khl -> later FG; [8,16M) vh; [16M..) Wqkv -> ofhi/oflo
  char* wsb = (char*)d_ws;
  unsigned short* khh  = (unsigned short*)wsb;
  unsigned short* khl  = (unsigned short*)(wsb + (4u << 20));
  float*          vh   = (float*)(wsb + (8u << 20));
  unsigned short* Wqkv = (unsigned short*)(wsb + (16u << 20));
  unsigned short* ofhi = (unsigned short*)(wsb + (16u << 20));
  unsigned short* oflo = (unsigned short*)(wsb + (20u << 20));
  unsigned short* FG   = (unsigned short*)wsb;

  zerofill_kernel<<<dim3(4096), 256, 0, stream>>>((float4*)attn, 1 << 23);
  convW_kernel<<<dim3(256, 1, 3), 256, 0, stream>>>(Wq, Wk, Wv, Wqkv);
  qkv_mfma_kernel<<<dim3(64, 4, 3), 256, 0, stream>>>(q, k, v, Wqkv, bq, bk, bv,
                                                      qhh, qhl, khh, khl, vh);
  fused_attn_kernel<<<dim3(2048), 512, 0, stream>>>(qhh, qhl, khh, khl, vh,
                                                    attn, ofhi, oflo);
  convW_kernel<<<dim3(256, 1, 2), 256, 0, stream>>>(Wfc, Wg, Wg, FG);
  out_proj_mfma_kernel<<<dim3(64, 4), 256, 0, stream>>>(ofhi, oflo, FG, bfc, bg, out);
}

// Round 11
// 134.375 us; speedup vs baseline: 1.5831x; 1.3070x over previous
//
#include <hip/hip_runtime.h>
#include <hip/hip_bf16.h>
#include <math.h>

#define OUT0   2097152      // 4*1024*512 (output 0 size)
#define SP_EPS 1e-7f
#define INV_T  0.125f       // 1/sqrt(64)
#define LOG2E  1.4426950408889634f

typedef __attribute__((ext_vector_type(8))) short bf16x8;
typedef __attribute__((ext_vector_type(4))) float f32x4;

// ---------------- bf16 split helpers (RN-to-nearest-even) ------------------
__device__ __forceinline__ unsigned short f2bf(float f) {
  unsigned int b = __float_as_uint(f);
  return (unsigned short)((b + 0x7fffu + ((b >> 16) & 1u)) >> 16);
}
__device__ __forceinline__ float bf2f(unsigned short u) {
  return __uint_as_float(((unsigned int)u) << 16);
}

__device__ __forceinline__ float wred_sum(float v) {
#pragma unroll
  for (int o = 32; o > 0; o >>= 1) v += __shfl_xor(v, o);
  return v;
}

// ---------------- kernel 0: split-convert up to 3 weight matrices ----------
__global__ __launch_bounds__(256) void convW_kernel(
    const float* __restrict__ w0, const float* __restrict__ w1,
    const float* __restrict__ w2, unsigned short* __restrict__ dst)
{
  const int z = blockIdx.z;
  const float* src = (z == 0) ? w0 : (z == 1) ? w1 : w2;
  unsigned short* hi = dst + (size_t)z * (1u << 19);
  unsigned short* lo = hi + (1u << 18);
  const int i = (blockIdx.x * 256 + threadIdx.x) * 4;
  const float4 x = *(const float4*)(src + i);
  ushort4 h, l;
  h.x = f2bf(x.x); l.x = f2bf(x.x - bf2f(h.x));
  h.y = f2bf(x.y); l.y = f2bf(x.y - bf2f(h.y));
  h.z = f2bf(x.z); l.z = f2bf(x.z - bf2f(h.z));
  h.w = f2bf(x.w); l.w = f2bf(x.w - bf2f(h.w));
  *(ushort4*)(hi + i) = h;
  *(ushort4*)(lo + i) = l;
}

// ---------------- kernel 1: QKV projection via split-bf16 MFMA -------------
// BM=64, BN=128, BK=64; 4 waves (2x2). A (q/k/v f32) split in-register during
// staging; W pre-split. q,k out as hi/lo bf16; v out f32.
__global__ __launch_bounds__(256) void qkv_mfma_kernel(
    const float* __restrict__ q, const float* __restrict__ k, const float* __restrict__ v,
    const unsigned short* __restrict__ Wsplit,
    const float* __restrict__ bq, const float* __restrict__ bk, const float* __restrict__ bv,
    unsigned short* __restrict__ qhh, unsigned short* __restrict__ qhl,
    unsigned short* __restrict__ khh, unsigned short* __restrict__ khl,
    float* __restrict__ vh)
{
  __shared__ short Ash[64 * 64], Asl[64 * 64];
  __shared__ short Bsh[128 * 64], Bsl[128 * 64];
  const int z = blockIdx.z;
  const float* A = (z == 0) ? q : (z == 1) ? k : v;
  const unsigned short* Wh = Wsplit + (size_t)z * (1u << 19);
  const unsigned short* Wl = Wh + (1u << 18);
  const float* bias = (z == 0) ? bq : (z == 1) ? bk : bv;
  const int r0 = blockIdx.x * 64, n0 = blockIdx.y * 128;
  const int tid = threadIdx.x, lane = tid & 63, w = tid >> 6;
  const int wr = w >> 1, wc = w & 1;
  const int l15 = lane & 15, l4 = lane >> 4;

  f32x4 acc[2][4];
#pragma unroll
  for (int a = 0; a < 2; ++a)
#pragma unroll
    for (int b = 0; b < 4; ++b) acc[a][b] = (f32x4){0.f, 0.f, 0.f, 0.f};

  for (int kt = 0; kt < 8; ++kt) {
    __syncthreads();
#pragma unroll
    for (int p = 0; p < 2; ++p) {
      const int c = tid + p * 256, row = c >> 3, k8 = (c & 7) * 8;
      const float4 x0 = *(const float4*)(A + (size_t)(r0 + row) * 512 + kt * 64 + k8);
      const float4 x1 = *(const float4*)(A + (size_t)(r0 + row) * 512 + kt * 64 + k8 + 4);
      bf16x8 hv, lv;
      const float xs[8] = {x0.x, x0.y, x0.z, x0.w, x1.x, x1.y, x1.z, x1.w};
#pragma unroll
      for (int j = 0; j < 8; ++j) {
        const unsigned short h = f2bf(xs[j]);
        hv[j] = (short)h; lv[j] = (short)f2bf(xs[j] - bf2f(h));
      }
      const int si = row * 64 + (k8 ^ ((row & 7) << 3));
      *(bf16x8*)&Ash[si] = hv; *(bf16x8*)&Asl[si] = lv;
    }
#pragma unroll
    for (int p = 0; p < 4; ++p) {
      const int c = tid + p * 256, row = c >> 3, k8 = (c & 7) * 8;
      const size_t go = (size_t)(n0 + row) * 512 + kt * 64 + k8;
      const int si = row * 64 + (k8 ^ ((row & 7) << 3));
      *(bf16x8*)&Bsh[si] = *(const bf16x8*)(Wh + go);
      *(bf16x8*)&Bsl[si] = *(const bf16x8*)(Wl + go);
    }
    __syncthreads();
#pragma unroll
    for (int kf = 0; kf < 2; ++kf) {
      const int kb = kf * 32 + l4 * 8;
      bf16x8 ah[2], al2[2];
#pragma unroll
      for (int rb = 0; rb < 2; ++rb) {
        const int ar = wr * 32 + rb * 16 + l15;
        const int si = ar * 64 + (kb ^ ((ar & 7) << 3));
        ah[rb] = *(bf16x8*)&Ash[si]; al2[rb] = *(bf16x8*)&Asl[si];
      }
#pragma unroll
      for (int cb = 0; cb < 4; ++cb) {
        const int br = wc * 64 + cb * 16 + l15;
        const int si = br * 64 + (kb ^ ((br & 7) << 3));
        const bf16x8 bh = *(bf16x8*)&Bsh[si];
        const bf16x8 bl = *(bf16x8*)&Bsl[si];
#pragma unroll
        for (int rb = 0; rb < 2; ++rb) {
          acc[rb][cb] = __builtin_amdgcn_mfma_f32_16x16x32_bf16(al2[rb], bh, acc[rb][cb], 0, 0, 0);
          acc[rb][cb] = __builtin_amdgcn_mfma_f32_16x16x32_bf16(ah[rb], bl, acc[rb][cb], 0, 0, 0);
          acc[rb][cb] = __builtin_amdgcn_mfma_f32_16x16x32_bf16(ah[rb], bh, acc[rb][cb], 0, 0, 0);
        }
      }
    }
  }
  unsigned short* H = (z == 0) ? qhh : khh;
  unsigned short* L = (z == 0) ? qhl : khl;
#pragma unroll
  for (int cb = 0; cb < 4; ++cb) {
    const int col = n0 + wc * 64 + cb * 16 + l15;
    const float bia = bias[col];
    const int h = col >> 6, d = col & 63;
#pragma unroll
    for (int rb = 0; rb < 2; ++rb)
#pragma unroll
      for (int ri = 0; ri < 4; ++ri) {
        const int row = r0 + wr * 32 + rb * 16 + l4 * 4 + ri;
        const int b = row >> 10, ll = row & 1023;
        const size_t idx = ((size_t)(h * 4 + b) << 16) + (ll << 6) + d;
        const float val = acc[rb][cb][ri] + bia;
        if (z == 2) {
          vh[idx] = val;
        } else {
          const unsigned short hv = f2bf(val);
          H[idx] = hv;
          L[idx] = f2bf(val - bf2f(hv));
        }
      }
  }
}

// ---------------- kernel 2: scores via split-bf16 MFMA ---------------------
// per bh: Q(1024x64) @ K(1024x64)^T / 8; BM=BN=64, K=64, 4 waves 2x2.
__global__ __launch_bounds__(256) void scores_mfma_kernel(
    const unsigned short* __restrict__ qhh, const unsigned short* __restrict__ qhl,
    const unsigned short* __restrict__ khh, const unsigned short* __restrict__ khl,
    float* __restrict__ attn)
{
  __shared__ short Qh[64 * 64], Ql[64 * 64], Kh[64 * 64], Kl[64 * 64];
  const int bh = blockIdx.z;
  const int r0 = blockIdx.x * 64, c0 = blockIdx.y * 64;
  const int tid = threadIdx.x, lane = tid & 63, w = tid >> 6;
  const int wr = w >> 1, wc = w & 1;
  const int l15 = lane & 15, l4 = lane >> 4;
  const size_t base = (size_t)bh << 16;
#pragma unroll
  for (int p = 0; p < 2; ++p) {
    const int c = tid + p * 256, row = c >> 3, k8 = (c & 7) * 8;
    const int si = row * 64 + (k8 ^ ((row & 7) << 3));
    *(bf16x8*)&Qh[si] = *(const bf16x8*)(qhh + base + (size_t)(r0 + row) * 64 + k8);
    *(bf16x8*)&Ql[si] = *(const bf16x8*)(qhl + base + (size_t)(r0 + row) * 64 + k8);
    *(bf16x8*)&Kh[si] = *(const bf16x8*)(khh + base + (size_t)(c0 + row) * 64 + k8);
    *(bf16x8*)&Kl[si] = *(const bf16x8*)(khl + base + (size_t)(c0 + row) * 64 + k8);
  }
  __syncthreads();
  f32x4 acc[2][2];
#pragma unroll
  for (int a = 0; a < 2; ++a)
#pragma unroll
    for (int b = 0; b < 2; ++b) acc[a][b] = (f32x4){0.f, 0.f, 0.f, 0.f};
#pragma unroll
  for (int kf = 0; kf < 2; ++kf) {
    const int kb = kf * 32 + l4 * 8;
    bf16x8 ah[2], al2[2];
#pragma unroll
    for (int rb = 0; rb < 2; ++rb) {
      const int ar = wr * 32 + rb * 16 + l15;
      const int si = ar * 64 + (kb ^ ((ar & 7) << 3));
      ah[rb] = *(bf16x8*)&Qh[si]; al2[rb] = *(bf16x8*)&Ql[si];
    }
#pragma unroll
    for (int cb = 0; cb < 2; ++cb) {
      const int br = wc * 32 + cb * 16 + l15;
      const int si = br * 64 + (kb ^ ((br & 7) << 3));
      const bf16x8 bh8 = *(bf16x8*)&Kh[si];
      const bf16x8 bl8 = *(bf16x8*)&Kl[si];
#pragma unroll
      for (int rb = 0; rb < 2; ++rb) {
        acc[rb][cb] = __builtin_amdgcn_mfma_f32_16x16x32_bf16(al2[rb], bh8, acc[rb][cb], 0, 0, 0);
        acc[rb][cb] = __builtin_amdgcn_mfma_f32_16x16x32_bf16(ah[rb], bl8, acc[rb][cb], 0, 0, 0);
        acc[rb][cb] = __builtin_amdgcn_mfma_f32_16x16x32_bf16(ah[rb], bh8, acc[rb][cb], 0, 0, 0);
      }
    }
  }
  float* outp = attn + ((size_t)bh << 20);
#pragma unroll
  for (int cb = 0; cb < 2; ++cb) {
    const int col = c0 + wc * 32 + cb * 16 + l15;
#pragma unroll
    for (int rb = 0; rb < 2; ++rb)
#pragma unroll
      for (int ri = 0; ri < 4; ++ri) {
        const int row = r0 + wr * 32 + rb * 16 + l4 * 4 + ri;
        outp[(size_t)row * 1024 + col] = acc[rb][cb][ri] * INV_T;
      }
  }
}

// ---------------- kernel 3: softmax + top-6 sparsify + sparse PV -----------
// Wave-synchronous, branch-free, NO max-subtraction (u = exp2(s8*log2e) is
// overflow-safe: |s/8| <~ 14). w = (u-u6-eps*Z)+ / (S+eps*Z) is exactly the
// reference formula divided through by Z.
__global__ __launch_bounds__(256) void sparse_row_kernel(
    float* __restrict__ attn, const float* __restrict__ vh,
    unsigned short* __restrict__ ofhi, unsigned short* __restrict__ oflo)
{
  const int tid  = threadIdx.x;
  const int wv   = tid >> 6, lane = tid & 63;
  const int row  = blockIdx.x * 4 + wv;          // bh*1024 + lq
  const int bh   = row >> 10, lq = row & 1023;
  float* rp = attn + ((size_t)row << 10);
  __shared__ float s_w[4][8];
  __shared__ int   s_i[4][8];

  float u[16];
  {
    const float4 t0 = *(const float4*)(rp + lane * 4);
    const float4 t1 = *(const float4*)(rp + 256 + lane * 4);
    const float4 t2 = *(const float4*)(rp + 512 + lane * 4);
    const float4 t3 = *(const float4*)(rp + 768 + lane * 4);
    u[0]=t0.x; u[1]=t0.y; u[2]=t0.z; u[3]=t0.w;
    u[4]=t1.x; u[5]=t1.y; u[6]=t1.z; u[7]=t1.w;
    u[8]=t2.x; u[9]=t2.y; u[10]=t2.z; u[11]=t2.w;
    u[12]=t3.x; u[13]=t3.y; u[14]=t3.z; u[15]=t3.w;
  }

  float Zl = 0.f;
#pragma unroll
  for (int j = 0; j < 16; ++j) { u[j] = exp2f(u[j] * LOG2E); Zl += u[j]; }
  const float Z = wred_sum(Zl);

  // lane-local top-6 sorted desc (insertion network, uniform)
  float t0 = -1e30f, t1 = -1e30f, t2 = -1e30f, t3 = -1e30f, t4 = -1e30f, t5 = -1e30f;
#pragma unroll
  for (int j = 0; j < 16; ++j) {
    float v = u[j], a;
    a = fmaxf(t0, v); v = fminf(t0, v); t0 = a;
    a = fmaxf(t1, v); v = fminf(t1, v); t1 = a;
    a = fmaxf(t2, v); v = fminf(t2, v); t2 = a;
    a = fmaxf(t3, v); v = fminf(t3, v); t3 = a;
    a = fmaxf(t4, v); v = fminf(t4, v); t4 = a;
    t5 = fmaxf(t5, v);
  }
  // butterfly merge of sorted-6 lists across 64 lanes
#pragma unroll
  for (int off = 1; off < 64; off <<= 1) {
    const float b0 = __shfl_xor(t0, off), b1 = __shfl_xor(t1, off),
                b2 = __shfl_xor(t2, off), b3 = __shfl_xor(t3, off),
                b4 = __shfl_xor(t4, off), b5 = __shfl_xor(t5, off);
    float m0 = fmaxf(t0, b5), m1 = fmaxf(t1, b4), m2 = fmaxf(t2, b3),
          m3 = fmaxf(t3, b2), m4 = fmaxf(t4, b1), m5 = fmaxf(t5, b0);
    float a;
    a = fmaxf(m0, m3); m3 = fminf(m0, m3); m0 = a;
    a = fmaxf(m1, m4); m4 = fminf(m1, m4); m1 = a;
    a = fmaxf(m2, m5); m5 = fminf(m2, m5); m2 = a;
    a = fmaxf(m0, m1); m1 = fminf(m0, m1); m0 = a;
    a = fmaxf(m0, m2); m2 = fminf(m0, m2); m0 = a;
    a = fmaxf(m1, m2); m2 = fminf(m1, m2); m1 = a;
    a = fmaxf(m3, m4); m4 = fminf(m3, m4); m3 = a;
    a = fmaxf(m3, m5); m5 = fminf(m3, m5); m3 = a;
    a = fmaxf(m4, m5); m5 = fminf(m4, m5); m4 = a;
    t0 = m0; t1 = m1; t2 = m2; t3 = m3; t4 = m4; t5 = m5;
  }

  const float du = t5 + SP_EPS * Z;
  float w[16], Sl = 0.f;
#pragma unroll
  for (int j = 0; j < 16; ++j) { w[j] = fmaxf(u[j] - du, 0.f); Sl += w[j]; }
  const float S = wred_sum(Sl);
  const float inv = 1.0f / (S + SP_EPS * Z);
#pragma unroll
  for (int j = 0; j < 16; ++j) w[j] *= inv;

  *(float4*)(rp +       lane * 4) = make_float4(w[0],  w[1],  w[2],  w[3]);
  *(float4*)(rp + 256 + lane * 4) = make_float4(w[4],  w[5],  w[6],  w[7]);
  *(float4*)(rp + 512 + lane * 4) = make_float4(w[8],  w[9],  w[10], w[11]);
  *(float4*)(rp + 768 + lane * 4) = make_float4(w[12], w[13], w[14], w[15]);

  int base = 0;
#pragma unroll
  for (int j = 0; j < 16; ++j) {
    const unsigned long long b = __ballot(w[j] > 0.f);
    if (w[j] > 0.f) {
      const int pos = base + __popcll(b & ((1ull << lane) - 1ull));
      if (pos < 8) { s_w[wv][pos] = w[j]; s_i[wv][pos] = (j >> 2) * 256 + lane * 4 + (j & 3); }
    }
    base += __popcll(b);
  }
  if (base > 8) base = 8;

  float acc = 0.f;
  const float* vb = vh + ((size_t)bh << 16);
  for (int t = 0; t < base; ++t)
    acc = fmaf(s_w[wv][t], vb[((size_t)s_i[wv][t] << 6) + lane], acc);
  const int b_ = bh & 3, h = bh >> 2;
  const int idx = (((b_ << 10) | lq) << 9) + (h << 6) + lane;
  const unsigned short hv = f2bf(acc);
  ofhi[idx] = hv;
  oflo[idx] = f2bf(acc - bf2f(hv));
}

// ---------------- kernel 4: fc+gate via split-bf16 MFMA + fused epilogue ---
__global__ __launch_bounds__(256) void out_proj_mfma_kernel(
    const unsigned short* __restrict__ ofhi, const unsigned short* __restrict__ oflo,
    const unsigned short* __restrict__ FG,
    const float* __restrict__ bfc, const float* __restrict__ bg,
    float* __restrict__ out)
{
  __shared__ short Ash[64 * 64], Asl[64 * 64];
  __shared__ short Bfh[128 * 64], Bfl[128 * 64];
  __shared__ short Bgh[128 * 64], Bgl[128 * 64];
  const unsigned short* Wfh = FG;
  const unsigned short* Wfl = FG + (1u << 18);
  const unsigned short* Wgh = FG + (2u << 18);
  const unsigned short* Wgl = FG + 3u * (1u << 18);
  const int r0 = blockIdx.x * 64, n0 = blockIdx.y * 128;
  const int tid = threadIdx.x, lane = tid & 63, w = tid >> 6;
  const int wr = w >> 1, wc = w & 1;
  const int l15 = lane & 15, l4 = lane >> 4;

  f32x4 accf[2][4], accg[2][4];
#pragma unroll
  for (int a = 0; a < 2; ++a)
#pragma unroll
    for (int b = 0; b < 4; ++b) {
      accf[a][b] = (f32x4){0.f, 0.f, 0.f, 0.f};
      accg[a][b] = (f32x4){0.f, 0.f, 0.f, 0.f};
    }

  for (int kt = 0; kt < 8; ++kt) {
    __syncthreads();
#pragma unroll
    for (int p = 0; p < 2; ++p) {
      const int c = tid + p * 256, row = c >> 3, k8 = (c & 7) * 8;
      const size_t go = (size_t)(r0 + row) * 512 + kt * 64 + k8;
      const int si = row * 64 + (k8 ^ ((row & 7) << 3));
      *(bf16x8*)&Ash[si] = *(const bf16x8*)(ofhi + go);
      *(bf16x8*)&Asl[si] = *(const bf16x8*)(oflo + go);
    }
#pragma unroll
    for (int p = 0; p < 4; ++p) {
      const int c = tid + p * 256, row = c >> 3, k8 = (c & 7) * 8;
      const int si = row * 64 + (k8 ^ ((row & 7) << 3));
      const size_t go = (size_t)(n0 + row) * 512 + kt * 64 + k8;
      *(bf16x8*)&Bfh[si] = *(const bf16x8*)(Wfh + go);
      *(bf16x8*)&Bfl[si] = *(const bf16x8*)(Wfl + go);
      *(bf16x8*)&Bgh[si] = *(const bf16x8*)(Wgh + go);
      *(bf16x8*)&Bgl[si] = *(const bf16x8*)(Wgl + go);
    }
    __syncthreads();
#pragma unroll
    for (int kf = 0; kf < 2; ++kf) {
      const int kb = kf * 32 + l4 * 8;
      bf16x8 ah[2], al2[2];
#pragma unroll
      for (int rb = 0; rb < 2; ++rb) {
        const int ar = wr * 32 + rb * 16 + l15;
        const int si = ar * 64 + (kb ^ ((ar & 7) << 3));
        ah[rb] = *(bf16x8*)&Ash[si]; al2[rb] = *(bf16x8*)&Asl[si];
      }
#pragma unroll
      for (int cb = 0; cb < 4; ++cb) {
        const int br = wc * 64 + cb * 16 + l15;
        const int si = br * 64 + (kb ^ ((br & 7) << 3));
        const bf16x8 fh = *(bf16x8*)&Bfh[si];
        const bf16x8 fl = *(bf16x8*)&Bfl[si];
        const bf16x8 gh = *(bf16x8*)&Bgh[si];
        const bf16x8 gl = *(bf16x8*)&Bgl[si];
#pragma unroll
        for (int rb = 0; rb < 2; ++rb) {
          accf[rb][cb] = __builtin_amdgcn_mfma_f32_16x16x32_bf16(al2[rb], fh, accf[rb][cb], 0, 0, 0);
          accf[rb][cb] = __builtin_amdgcn_mfma_f32_16x16x32_bf16(ah[rb], fl, accf[rb][cb], 0, 0, 0);
          accf[rb][cb] = __builtin_amdgcn_mfma_f32_16x16x32_bf16(ah[rb], fh, accf[rb][cb], 0, 0, 0);
          accg[rb][cb] = __builtin_amdgcn_mfma_f32_16x16x32_bf16(al2[rb], gh, accg[rb][cb], 0, 0, 0);
          accg[rb][cb] = __builtin_amdgcn_mfma_f32_16x16x32_bf16(ah[rb], gl, accg[rb][cb], 0, 0, 0);
          accg[rb][cb] = __builtin_amdgcn_mfma_f32_16x16x32_bf16(ah[rb], gh, accg[rb][cb], 0, 0, 0);
        }
      }
    }
  }
#pragma unroll
  for (int cb = 0; cb < 4; ++cb) {
    const int col = n0 + wc * 64 + cb * 16 + l15;
    const float bf4 = bfc[col];
    const float bg4 = bg[col];
#pragma unroll
    for (int rb = 0; rb < 2; ++rb)
#pragma unroll
      for (int ri = 0; ri < 4; ++ri) {
        const int row = r0 + wr * 32 + rb * 16 + l4 * 4 + ri;
        const float f = accf[rb][cb][ri] + bf4;
        const float g = accg[rb][cb][ri] + bg4;
        out[(size_t)row * 512 + col] = tanhf(f) / (1.f + __expf(-g));
      }
  }
}

extern "C" void kernel_launch(void* const* d_in, const int* in_sizes, int n_in,
                              void* d_out, int out_size, void* d_ws, size_t ws_size,
                              hipStream_t stream) {
  const float* q   = (const float*)d_in[0];
  const float* k   = (const float*)d_in[1];
  const float* v   = (const float*)d_in[2];
  const float* Wq  = (const float*)d_in[3];
  const float* bq  = (const float*)d_in[4];
  const float* Wk  = (const float*)d_in[5];
  const float* bk  = (const float*)d_in[6];
  const float* Wv  = (const float*)d_in[7];
  const float* bv  = (const float*)d_in[8];
  const float* Wfc = (const float*)d_in[9];
  const float* bfc = (const float*)d_in[10];
  const float* Wg  = (const float*)d_in[11];
  const float* bg  = (const float*)d_in[12];

  float* out  = (float*)d_out;
  float* attn = out + OUT0;                 // (32,1024,1024) score scratch then final

  // qh splits live in the out0 region (8MB, overwritten by out_proj at the end)
  unsigned short* qhh = (unsigned short*)d_out;
  unsigned short* qhl = qhh + (1u << 21);

  // ws (24MB): [0,8M) khh/khl -> later FG; [8,16M) vh; [16M..) Wqkv -> ofhi/oflo
  char* wsb = (char*)d_ws;
  unsigned short* khh  = (unsigned short*)wsb;
  unsigned short* khl  = (unsigned short*)(wsb + (4u << 20));
  float*          vh   = (float*)(wsb + (8u << 20));
  unsigned short* Wqkv = (unsigned short*)(wsb + (16u << 20));
  unsigned short* ofhi = (unsigned short*)(wsb + (16u << 20));
  unsigned short* oflo = (unsigned short*)(wsb + (20u << 20));
  unsigned short* FG   = (unsigned short*)wsb;

  convW_kernel<<<dim3(256, 1, 3), 256, 0, stream>>>(Wq, Wk, Wv, Wqkv);
  qkv_mfma_kernel<<<dim3(64, 4, 3), 256, 0, stream>>>(q, k, v, Wqkv, bq, bk, bv,
                                                      qhh, qhl, khh, khl, vh);
  scores_mfma_kernel<<<dim3(16, 16, 32), 256, 0, stream>>>(qhh, qhl, khh, khl, attn);
  convW_kernel<<<dim3(256, 1, 2), 256, 0, stream>>>(Wfc, Wg, Wg, FG);
  sparse_row_kernel<<<dim3(8192), 256, 0, stream>>>(attn, vh, ofhi, oflo);
  out_proj_mfma_kernel<<<dim3(64, 4), 256, 0, stream>>>(ofhi, oflo, FG, bfc, bg, out);
}